// Round 11
// baseline (91.338 us; speedup 1.0000x reference)
//
#include <hip/hip_runtime.h>

typedef unsigned int uint32;
typedef unsigned short ushort;

typedef __bf16  bf16x8   __attribute__((ext_vector_type(8)));
typedef float   f32x4    __attribute__((ext_vector_type(4)));
typedef ushort  ushort4v __attribute__((ext_vector_type(4)));

#define K_CODES 1024
#define CDIM    64
#define HWALL   4096      // H*W
#define CHW     262144    // CDIM*HWALL
#define TROWS   64        // z-rows per tile (4 tiles per block)

__device__ __forceinline__ ushort f2bf(float f) {
    uint32 u = __builtin_bit_cast(uint32, f);
    u += 0x7FFFu + ((u >> 16) & 1u);   // RNE
    return (ushort)(u >> 16);
}

// Pass 0 (tiny, coalesced): codebook fp32 -> bf16 row-major + negbias[k] =
// -0.5*||e_k||^2. Also zeroes the loss cell out[0].
// (R9 lesson: fusing this into vq_kernel makes the fp32 B loads lane-strided
//  256B/uncoalesced -- keep the separate dispatch.)
__global__ __launch_bounds__(256) void prep_kernel(const float* __restrict__ cb,
                                                   ushort* __restrict__ cbb,
                                                   float* __restrict__ negbias,
                                                   float* __restrict__ out) {
    int t = threadIdx.x;
    if (blockIdx.x == 0 && t == 0) out[0] = 0.f;
    int k = blockIdx.x * 4 + (t >> 6);
    int c = t & 63;
    float v = cb[k * 64 + c];
    cbb[k * 64 + c] = f2bf(v);
    float s = v * v;
    #pragma unroll
    for (int d = 1; d < 64; d <<= 1) s += __shfl_xor(s, d, 64);
    if (c == 0) negbias[k] = -0.5f * s;
}

// Main: 256 blocks (1/CU) x 1024 threads (16 waves), FOUR 64-row tiles,
// software-pipelined (R10 schedule generalized):
//   per tile i: gemm_i -> barrier -> combine+issue gather_i -> restage_{i+1}
//   -> barrier -> consume_i (stores overlap gemm_{i+1}).
// z issue staggered: z0,z1 upfront; z2 during gemm0; z3 during gemm1 -- the
// first barrier waits on ~32KB/CU not 64KB. Tail store = 4.2MB (was 8.4).
// B-regs (wave w: n-tiles [w*4,+4), 32 VGPRs + 4 nb) load once from bf16 cbb.
__global__ __launch_bounds__(1024, 4) void vq_kernel(const float* __restrict__ z,
                                                     const ushort* __restrict__ cbb,
                                                     const float* __restrict__ negbias,
                                                     float* __restrict__ out) {
    __shared__ __align__(16) ushort Abf[TROWS * 72];  // 9 KB A-tile, pitch 72
    __shared__ float partial[16][TROWS];              // 4 KB packed argmax keys
    __shared__ float loss_acc;

    const int t   = threadIdx.x;
    const int blk = blockIdx.x;
    const int b   = blk >> 4;
    const int hw0 = (blk & 15) << 8;          // 256 rows per block
    const int zoff0 = b * CHW + hw0;

    if (t == 0) loss_acc = 0.f;

    const int r  = t & 63;     // z-row within tile (lanes consecutive -> coalesced)
    const int cq = t >> 6;     // c-quad 0..15: channels cq*4 .. cq*4+3
    const int w  = t >> 6;     // wave 0..15: owns n-tiles [w*4, +4)
    const int l  = t & 63;
    const int m  = l & 15;     // B col within n-tile / A row within m-block
    const int q  = l >> 4;     // k-quad

    // ---- issue tile-0 and tile-1 z loads (tile-0 most urgent) ----
    float zv[4][4];
    #pragma unroll
    for (int j = 0; j < 4; ++j) zv[0][j] = z[zoff0       + (cq * 4 + j) * HWALL + r];
    #pragma unroll
    for (int j = 0; j < 4; ++j) zv[1][j] = z[zoff0 + 64  + (cq * 4 + j) * HWALL + r];

    // ---- load this wave's codebook slice into registers (once, from bf16) ----
    bf16x8 Bv[4][2];
    float  nb[4];
    #pragma unroll
    for (int j = 0; j < 4; ++j) {
        int col = (((w << 2) + j) << 4) + m;
        Bv[j][0] = *(const bf16x8*)&cbb[(col << 6) + (q << 3)];
        Bv[j][1] = *(const bf16x8*)&cbb[(col << 6) + 32 + (q << 3)];
        nb[j] = negbias[col];
    }

    // ---- stage tile-0 -> Abf (bf16, pitch 72; 8B write per thread) ----
    {
        ushort4v pk;
        #pragma unroll
        for (int j = 0; j < 4; ++j) pk[j] = f2bf(zv[0][j]);
        *(ushort4v*)&Abf[r * 72 + cq * 4] = pk;
    }
    __syncthreads();

    float lsum = 0.f;

    // GEMM over current 64-row Abf: 4 m-blocks x this wave's 4 n-tiles (reg-B),
    // packed-key argmax -> partial[w][0..63].
    auto do_gemm = [&]() {
        float best[16];
        #pragma unroll
        for (int i = 0; i < 16; ++i) best[i] = -__builtin_inff();
        #pragma unroll
        for (int mbb = 0; mbb < 4; ++mbb) {
            bf16x8 a0 = *(const bf16x8*)&Abf[(mbb * 16 + m) * 72 + (q << 3)];
            bf16x8 a1 = *(const bf16x8*)&Abf[(mbb * 16 + m) * 72 + 32 + (q << 3)];
            #pragma unroll
            for (int j = 0; j < 4; ++j) {
                uint32 tag = 1023u - (uint32)(((((w << 2) + j) << 4)) + m);
                f32x4 acc0;
                acc0[0] = nb[j]; acc0[1] = nb[j]; acc0[2] = nb[j]; acc0[3] = nb[j];
                f32x4 acc = __builtin_amdgcn_mfma_f32_16x16x32_bf16(a0, Bv[j][0], acc0, 0, 0, 0);
                acc       = __builtin_amdgcn_mfma_f32_16x16x32_bf16(a1, Bv[j][1], acc,  0, 0, 0);
                #pragma unroll
                for (int rr = 0; rr < 4; ++rr) {
                    uint32 kb = (__builtin_bit_cast(uint32, acc[rr]) & 0xFFFFFC00u) | tag;
                    best[mbb * 4 + rr] = fmaxf(best[mbb * 4 + rr], __builtin_bit_cast(float, kb));
                }
            }
        }
        // reduce across the 16 cols (lanes sharing q) and store keys
        #pragma unroll
        for (int i = 0; i < 16; ++i) {
            float v = best[i];
            #pragma unroll
            for (int d = 1; d < 16; d <<= 1) v = fmaxf(v, __shfl_xor(v, d, 64));
            best[i] = v;
        }
        if (m == 0) {
            #pragma unroll
            for (int mbb = 0; mbb < 4; ++mbb)
                #pragma unroll
                for (int rr = 0; rr < 4; ++rr)
                    partial[w][mbb * 16 + (q << 2) + rr] = best[mbb * 4 + rr];
        }
    };

    #pragma unroll
    for (int T = 0; T < 4; ++T) {
        // stagger the z-load stream: tile T+2 issues while gemm_T runs
        if (T + 2 < 4) {
            #pragma unroll
            for (int j = 0; j < 4; ++j)
                zv[T + 2][j] = z[zoff0 + (T + 2) * 64 + (cq * 4 + j) * HWALL + r];
        }

        do_gemm();
        __syncthreads();

        // combine + issue gather (bf16 codebook, 8B); latency hides under restage
        ushort4v ec;
        {
            float km = partial[0][r];
            #pragma unroll
            for (int j = 1; j < 16; ++j) km = fmaxf(km, partial[j][r]);
            int idx = 1023 - (int)(__builtin_bit_cast(uint32, km) & 1023u);
            ec = *(const ushort4v*)&cbb[(idx << 6) + (cq << 2)];
        }

        // restage next tile (this tile's zp lives in regs; Abf free)
        if (T + 1 < 4) {
            ushort4v pk;
            #pragma unroll
            for (int j = 0; j < 4; ++j) pk[j] = f2bf(zv[T + 1][j]);
            *(ushort4v*)&Abf[r * 72 + cq * 4] = pk;
        }
        __syncthreads();

        // consume tile T: stores retire async while gemm_{T+1} runs
        #pragma unroll
        for (int j = 0; j < 4; ++j) {
            float v0 = __builtin_bit_cast(float, (uint32)ec[j] << 16);
            out[1 + zoff0 + T * 64 + (cq * 4 + j) * HWALL + r] = v0;  // ST fwd == vq
            float d0 = v0 - zv[T][j];
            lsum += d0 * d0;
        }
    }

    // ---- loss: wave reduce -> LDS -> one global atomic per block ----
    #pragma unroll
    for (int d = 1; d < 64; d <<= 1) lsum += __shfl_xor(lsum, d, 64);
    if (l == 0) atomicAdd(&loss_acc, lsum);
    __syncthreads();
    if (t == 0) atomicAdd(out, loss_acc * (1.25f / 4194304.f));  // (1+BETA)/numel
}

extern "C" void kernel_launch(void* const* d_in, const int* in_sizes, int n_in,
                              void* d_out, int out_size, void* d_ws, size_t ws_size,
                              hipStream_t stream) {
    (void)in_sizes; (void)n_in; (void)out_size; (void)ws_size;
    const float* z  = (const float*)d_in[0];
    const float* cb = (const float*)d_in[1];
    float* out = (float*)d_out;
    ushort* cbb = (ushort*)d_ws;
    float* negbias = (float*)((char*)d_ws + K_CODES * CDIM * sizeof(ushort));

    prep_kernel<<<dim3(256), dim3(256), 0, stream>>>(cb, cbb, negbias, out);
    vq_kernel<<<dim3(256), dim3(1024), 0, stream>>>(z, cbb, negbias, out);
}

// Round 12
// 86.689 us; speedup vs baseline: 1.0536x; 1.0536x over previous
//
#include <hip/hip_runtime.h>

typedef unsigned int uint32;
typedef unsigned short ushort;

typedef __bf16  bf16x8   __attribute__((ext_vector_type(8)));
typedef float   f32x4    __attribute__((ext_vector_type(4)));
typedef ushort  ushort4v __attribute__((ext_vector_type(4)));

#define K_CODES 1024
#define CDIM    64
#define HWALL   4096      // H*W
#define CHW     262144    // CDIM*HWALL
#define TROWS   128       // z-rows per tile (2 tiles per block)

__device__ __forceinline__ ushort f2bf(float f) {
    uint32 u = __builtin_bit_cast(uint32, f);
    u += 0x7FFFu + ((u >> 16) & 1u);   // RNE
    return (ushort)(u >> 16);
}

// Pass 0 (tiny, coalesced): codebook fp32 -> bf16 row-major + negbias[k] =
// -0.5*||e_k||^2. Also zeroes the loss cell out[0].
// (R9 lesson: fusing this into vq_kernel makes the fp32 B loads lane-strided
//  256B/uncoalesced -- keep the separate dispatch.)
__global__ __launch_bounds__(256) void prep_kernel(const float* __restrict__ cb,
                                                   ushort* __restrict__ cbb,
                                                   float* __restrict__ negbias,
                                                   float* __restrict__ out) {
    int t = threadIdx.x;
    if (blockIdx.x == 0 && t == 0) out[0] = 0.f;
    int k = blockIdx.x * 4 + (t >> 6);
    int c = t & 63;
    float v = cb[k * 64 + c];
    cbb[k * 64 + c] = f2bf(v);
    float s = v * v;
    #pragma unroll
    for (int d = 1; d < 64; d <<= 1) s += __shfl_xor(s, d, 64);
    if (c == 0) negbias[k] = -0.5f * s;
}

// Main: 256 blocks (1/CU) x 1024 threads (16 waves), two 128-row tiles,
// software-pipelined. Depth-2 is the measured optimum of this family
// (depth-1 R6: 90.1, depth-2 R10: 86.8, depth-4 R11: 91.3 -- per-tile fixed
// cost [combine+gather+restage+2 barriers] is constant, so deeper pipelines
// pay it more often for a sub-1us tail saving).
// Schedule per tile: gemm -> barrier -> combine+ISSUE GATHER -> restage next
// -> barrier -> consume (stores overlap next gemm on the VMEM pipe).
// B-regs (wave w: n-tiles [w*4,+4), 32 VGPRs + 4 nb) load once from bf16 cbb.
__global__ __launch_bounds__(1024, 4) void vq_kernel(const float* __restrict__ z,
                                                     const ushort* __restrict__ cbb,
                                                     const float* __restrict__ negbias,
                                                     float* __restrict__ out) {
    __shared__ __align__(16) ushort Abf[TROWS * 72];  // 18 KB A-tile, pitch 72
    __shared__ float partial[16][TROWS];              // 8 KB packed argmax keys
    __shared__ float loss_acc;

    const int t   = threadIdx.x;
    const int blk = blockIdx.x;
    const int b   = blk >> 4;
    const int hw0 = (blk & 15) << 8;          // 256 rows per block
    const int zoff0 = b * CHW + hw0;

    if (t == 0) loss_acc = 0.f;

    const int r  = t & 127;    // z-row within tile (lanes consecutive -> coalesced)
    const int cg = t >> 7;     // c-group 0..7
    const int w  = t >> 6;     // wave 0..15: owns n-tiles [w*4, +4)
    const int l  = t & 63;
    const int m  = l & 15;     // B col within n-tile / A row within m-block
    const int q  = l >> 4;     // k-quad

    // ---- issue tile-0 z loads (deepest dep) ----
    float z0v[8];
    #pragma unroll
    for (int j = 0; j < 8; ++j) z0v[j] = z[zoff0 + (cg * 8 + j) * HWALL + r];

    // ---- load this wave's codebook slice into registers (once, from bf16) ----
    bf16x8 Bv[4][2];
    float  nb[4];
    #pragma unroll
    for (int j = 0; j < 4; ++j) {
        int col = (((w << 2) + j) << 4) + m;
        Bv[j][0] = *(const bf16x8*)&cbb[(col << 6) + (q << 3)];
        Bv[j][1] = *(const bf16x8*)&cbb[(col << 6) + 32 + (q << 3)];
        nb[j] = negbias[col];
    }

    // ---- issue tile-1 z loads; they arrive during tile-0 GEMM ----
    float z1v[8];
    #pragma unroll
    for (int j = 0; j < 8; ++j) z1v[j] = z[zoff0 + 128 + (cg * 8 + j) * HWALL + r];

    // ---- stage tile-0 -> Abf (bf16, pitch 72) ----
    {
        ushort4v pk0, pk1;
        #pragma unroll
        for (int j = 0; j < 4; ++j) { pk0[j] = f2bf(z0v[j]); pk1[j] = f2bf(z0v[4 + j]); }
        *(ushort4v*)&Abf[r * 72 + cg * 8]     = pk0;
        *(ushort4v*)&Abf[r * 72 + cg * 8 + 4] = pk1;
    }
    __syncthreads();

    float lsum = 0.f;

    // GEMM over current Abf: 8 m-blocks x this wave's 4 n-tiles (reg-B),
    // packed-key argmax -> partial[w][0..127].
    auto do_gemm = [&]() {
        float best[16];
        #pragma unroll
        for (int i = 0; i < 16; ++i) best[i] = -__builtin_inff();
        #pragma unroll
        for (int mbb = 0; mbb < 8; ++mbb) {
            bf16x8 a0 = *(const bf16x8*)&Abf[(mbb * 16 + m) * 72 + (q << 3)];
            bf16x8 a1 = *(const bf16x8*)&Abf[(mbb * 16 + m) * 72 + 32 + (q << 3)];
            #pragma unroll
            for (int j = 0; j < 4; ++j) {
                uint32 tag = 1023u - (uint32)(((((w << 2) + j) << 4)) + m);
                f32x4 acc0;
                acc0[0] = nb[j]; acc0[1] = nb[j]; acc0[2] = nb[j]; acc0[3] = nb[j];
                f32x4 acc = __builtin_amdgcn_mfma_f32_16x16x32_bf16(a0, Bv[j][0], acc0, 0, 0, 0);
                acc       = __builtin_amdgcn_mfma_f32_16x16x32_bf16(a1, Bv[j][1], acc,  0, 0, 0);
                #pragma unroll
                for (int rr = 0; rr < 4; ++rr) {
                    uint32 kb = (__builtin_bit_cast(uint32, acc[rr]) & 0xFFFFFC00u) | tag;
                    int bi = (mbb & 3) * 4 + rr;
                    best[bi] = fmaxf(best[bi], __builtin_bit_cast(float, kb));
                }
            }
            if ((mbb & 3) == 3) {   // checkpoint: reduce + store 4 m-blocks
                #pragma unroll
                for (int i = 0; i < 16; ++i) {
                    float v = best[i];
                    #pragma unroll
                    for (int d = 1; d < 16; d <<= 1) v = fmaxf(v, __shfl_xor(v, d, 64));
                    best[i] = v;
                }
                if (m == 0) {
                    int base = (mbb - 3) * 16;
                    #pragma unroll
                    for (int mb2 = 0; mb2 < 4; ++mb2)
                        #pragma unroll
                        for (int rr = 0; rr < 4; ++rr)
                            partial[w][base + mb2 * 16 + (q << 2) + rr] = best[mb2 * 4 + rr];
                }
                #pragma unroll
                for (int i = 0; i < 16; ++i) best[i] = -__builtin_inff();
            }
        }
    };

    // ================= tile 0 =================
    do_gemm();
    __syncthreads();

    // combine + issue gather (bf16 codebook, 2x8B); latency hides under restage
    ushort4v ec0, ec1;
    {
        float km = partial[0][r];
        #pragma unroll
        for (int j = 1; j < 16; ++j) km = fmaxf(km, partial[j][r]);
        int idx0 = 1023 - (int)(__builtin_bit_cast(uint32, km) & 1023u);
        ec0 = *(const ushort4v*)&cbb[(idx0 << 6) + (cg << 3)];
        ec1 = *(const ushort4v*)&cbb[(idx0 << 6) + (cg << 3) + 4];
    }

    // restage tile-1 (tile-0 zp lives in z0v regs, Abf free to overwrite)
    {
        ushort4v pk0, pk1;
        #pragma unroll
        for (int j = 0; j < 4; ++j) { pk0[j] = f2bf(z1v[j]); pk1[j] = f2bf(z1v[4 + j]); }
        *(ushort4v*)&Abf[r * 72 + cg * 8]     = pk0;
        *(ushort4v*)&Abf[r * 72 + cg * 8 + 4] = pk1;
    }
    __syncthreads();

    // consume tile-0: stores retire async while gemm1 runs on the MFMA pipe
    #pragma unroll
    for (int j = 0; j < 4; ++j) {
        float v0 = __builtin_bit_cast(float, (uint32)ec0[j] << 16);
        float v1 = __builtin_bit_cast(float, (uint32)ec1[j] << 16);
        out[1 + zoff0 + (cg * 8 + j) * HWALL + r]     = v0;   // ST fwd == vq
        out[1 + zoff0 + (cg * 8 + 4 + j) * HWALL + r] = v1;
        float d0 = v0 - z0v[j], d1 = v1 - z0v[4 + j];
        lsum += d0 * d0 + d1 * d1;
    }

    // ================= tile 1 =================
    do_gemm();
    __syncthreads();

    {
        float km = partial[0][r];
        #pragma unroll
        for (int j = 1; j < 16; ++j) km = fmaxf(km, partial[j][r]);
        int idx1 = 1023 - (int)(__builtin_bit_cast(uint32, km) & 1023u);
        ushort4v f0 = *(const ushort4v*)&cbb[(idx1 << 6) + (cg << 3)];
        ushort4v f1 = *(const ushort4v*)&cbb[(idx1 << 6) + (cg << 3) + 4];
        #pragma unroll
        for (int j = 0; j < 4; ++j) {
            float v0 = __builtin_bit_cast(float, (uint32)f0[j] << 16);
            float v1 = __builtin_bit_cast(float, (uint32)f1[j] << 16);
            out[1 + zoff0 + 128 + (cg * 8 + j) * HWALL + r]     = v0;
            out[1 + zoff0 + 128 + (cg * 8 + 4 + j) * HWALL + r] = v1;
            float d0 = v0 - z1v[j], d1 = v1 - z1v[4 + j];
            lsum += d0 * d0 + d1 * d1;
        }
    }

    // ---- loss: wave reduce -> LDS -> one global atomic per block ----
    #pragma unroll
    for (int d = 1; d < 64; d <<= 1) lsum += __shfl_xor(lsum, d, 64);
    if (l == 0) atomicAdd(&loss_acc, lsum);
    __syncthreads();
    if (t == 0) atomicAdd(out, loss_acc * (1.25f / 4194304.f));  // (1+BETA)/numel
}

extern "C" void kernel_launch(void* const* d_in, const int* in_sizes, int n_in,
                              void* d_out, int out_size, void* d_ws, size_t ws_size,
                              hipStream_t stream) {
    (void)in_sizes; (void)n_in; (void)out_size; (void)ws_size;
    const float* z  = (const float*)d_in[0];
    const float* cb = (const float*)d_in[1];
    float* out = (float*)d_out;
    ushort* cbb = (ushort*)d_ws;
    float* negbias = (float*)((char*)d_ws + K_CODES * CDIM * sizeof(ushort));

    prep_kernel<<<dim3(256), dim3(256), 0, stream>>>(cb, cbb, negbias, out);
    vq_kernel<<<dim3(256), dim3(1024), 0, stream>>>(z, cbb, negbias, out);
}